// Round 6
// baseline (732.523 us; speedup 1.0000x reference)
//
#include <hip/hip_runtime.h>
#include <stdint.h>

// DPMultiheadAttention, MI355X bf16-MFMA implementation. Round 5 (resubmit).
// L=2048, N=4, E=1024, H=16, D=64.
// Q pre-scaled by D^-0.5*log2(e); softmax in exp2 domain.
// R5 change: k_avg only — occupancy fix. acc[2][8] (64 VGPR) -> acc[4]
// (16 VGPR) via s-tile split; 1/(16 l) folded into the exponent via
// ms2 = m + log2(16 l); __launch_bounds__(512,8) targets 8 waves/SIMD.

typedef __attribute__((ext_vector_type(8))) short bf16x8;
typedef __attribute__((ext_vector_type(4))) short s16x4;
typedef __attribute__((ext_vector_type(4))) float f32x4;

#define MFMA(a, b, c) __builtin_amdgcn_mfma_f32_16x16x32_bf16((a), (b), (c), 0, 0, 0)

__device__ __forceinline__ ushort f2bf(float f) {
    uint32_t u = __builtin_bit_cast(uint32_t, f);
    u += 0x7fffu + ((u >> 16) & 1u);   // round-to-nearest-even
    return (ushort)(u >> 16);
}

// ---------------------------------------------------------------------------
// K0: f32 -> bf16 pre-conversion (X: z=0..2, W: z=3..6). Memory-bound.
// ---------------------------------------------------------------------------
__global__ __launch_bounds__(256) void k_prep(
    const float* __restrict__ xq, const float* __restrict__ xk, const float* __restrict__ xv,
    const float* __restrict__ wq, const float* __restrict__ wk,
    const float* __restrict__ wv, const float* __restrict__ wo,
    ushort* __restrict__ xqb, ushort* __restrict__ xkb, ushort* __restrict__ xvb,
    ushort* __restrict__ wqb, ushort* __restrict__ wkb,
    ushort* __restrict__ wvb, ushort* __restrict__ wob)
{
    const int z = blockIdx.y;
    const float* src; ushort* dst; int n8;
    switch (z) {
        case 0: src = xq; dst = xqb; n8 = 1048576; break;
        case 1: src = xk; dst = xkb; n8 = 1048576; break;
        case 2: src = xv; dst = xvb; n8 = 1048576; break;
        case 3: src = wq; dst = wqb; n8 = 131072;  break;
        case 4: src = wk; dst = wkb; n8 = 131072;  break;
        case 5: src = wv; dst = wvb; n8 = 131072;  break;
        default: src = wo; dst = wob; n8 = 131072; break;
    }
    int u = blockIdx.x * 256 + threadIdx.x;
    if (u >= n8) return;
    const float4* s4 = (const float4*)src;
    float4 a = s4[2 * (size_t)u];
    float4 b = s4[2 * (size_t)u + 1];
    uint4 o;
    o.x = (uint)f2bf(a.x) | ((uint)f2bf(a.y) << 16);
    o.y = (uint)f2bf(a.z) | ((uint)f2bf(a.w) << 16);
    o.z = (uint)f2bf(b.x) | ((uint)f2bf(b.y) << 16);
    o.w = (uint)f2bf(b.z) | ((uint)f2bf(b.w) << 16);
    *(uint4*)(dst + 8 * (size_t)u) = o;
}

// ---------------------------------------------------------------------------
// K1: QKV projections from bf16 inputs. z=0: Q (scaled), z=1: K, z=2: V
// (V transposed by swapping A/B roles -> Vt[bh][d][s]).
// ---------------------------------------------------------------------------
__global__ __launch_bounds__(256) void k_proj(
    const ushort* __restrict__ Xq, const ushort* __restrict__ Xk, const ushort* __restrict__ Xv,
    const ushort* __restrict__ Wqb, const ushort* __restrict__ Wkb, const ushort* __restrict__ Wvb,
    const float* __restrict__ bq, const float* __restrict__ bk, const float* __restrict__ bv,
    ushort* __restrict__ Qa, ushort* __restrict__ Ka, ushort* __restrict__ Vt)
{
    const int z = blockIdx.z;
    const ushort* X = (z == 0) ? Xq : (z == 1) ? Xk : Xv;
    const ushort* W = (z == 0) ? Wqb : (z == 1) ? Wkb : Wvb;
    const float* B = (z == 0) ? bq : (z == 1) ? bk : bv;

    __shared__ __align__(16) ushort xt[128][40];   // +8 pad
    __shared__ __align__(16) ushort wt[128][40];

    const int t = threadIdx.x;
    const int lane = t & 63;
    const int w = t >> 6;
    const int wr = w >> 1, wc = w & 1;
    const int c = lane & 15, g = lane >> 4;

    const int xrow0 = blockIdx.x * 128;
    const int wrow0 = blockIdx.y * 128;

    f32x4 acc[4][4] = {};

    for (int kt = 0; kt < 32; ++kt) {
        const int k0 = kt * 32;
        __syncthreads();
#pragma unroll
        for (int i = 0; i < 2; ++i) {
            int slot = t + i * 256;
            int row = slot >> 2, seg = slot & 3;
            *(uint4*)&xt[row][seg * 8] =
                *(const uint4*)(X + (size_t)(xrow0 + row) * 1024 + k0 + seg * 8);
            *(uint4*)&wt[row][seg * 8] =
                *(const uint4*)(W + (size_t)(wrow0 + row) * 1024 + k0 + seg * 8);
        }
        __syncthreads();

        const ushort (*At)[40] = (z == 2) ? wt : xt;
        const ushort (*Bt)[40] = (z == 2) ? xt : wt;
        bf16x8 af[4], bfr[4];
#pragma unroll
        for (int m = 0; m < 4; ++m) af[m]  = *(const bf16x8*)&At[wr * 64 + m * 16 + c][g * 8];
#pragma unroll
        for (int n = 0; n < 4; ++n) bfr[n] = *(const bf16x8*)&Bt[wc * 64 + n * 16 + c][g * 8];
#pragma unroll
        for (int m = 0; m < 4; ++m)
#pragma unroll
            for (int n = 0; n < 4; ++n)
                acc[m][n] = MFMA(af[m], bfr[n], acc[m][n]);
    }

    const float QS = 0.125f * 1.44269504088896340736f;
#pragma unroll
    for (int m = 0; m < 4; ++m)
#pragma unroll
        for (int n = 0; n < 4; ++n)
#pragma unroll
            for (int i = 0; i < 4; ++i) {
                int rowi = ((z == 2) ? wrow0 : xrow0) + wr * 64 + m * 16 + 4 * g + i;
                int coli = ((z == 2) ? xrow0 : wrow0) + wc * 64 + n * 16 + c;
                int e = (z == 2) ? rowi : coli;
                int r = (z == 2) ? coli : rowi;
                float v = acc[m][n][i] + B[e];
                if (z == 0) v *= QS;
                ushort bv16 = f2bf(v);
                int nn = r & 3, l = r >> 2, h = e >> 6, d = e & 63;
                int bh = nn * 16 + h;
                if (z == 2) Vt[((size_t)bh * 64 + d) * 2048 + l] = bv16;
                else {
                    ushort* o = (z == 0) ? Qa : Ka;
                    o[((size_t)bh * 2048 + l) * 64 + d] = bv16;
                }
            }
}

// ---------------------------------------------------------------------------
// K2: flash attention, swapped-operand form. Per wave: 16 q rows (q=lane&15),
// KV tile 64. Scores S^T = mfma(K,Q): lane holds S[kv=ct*16+4g+r][q=c].
// Softmax fully lane-local (+2 shfl_xor for cross-group max/sum).
// PV as O^T = mfma(V^T, P): lane holds O[q=c][d=dt*16+4g+r] -> local rescale.
// ---------------------------------------------------------------------------
__global__ __launch_bounds__(512) void k_attn(
    const ushort* __restrict__ Qa, const ushort* __restrict__ Ka, const ushort* __restrict__ Vt,
    ushort* __restrict__ ctx, float* __restrict__ mbuf, float* __restrict__ lbuf)
{
    // smem: kt[64][72] | vt[64][72] | pt: 8 waves x [16][72]
    __shared__ __align__(16) ushort smem[4608 * 2 + 8 * 16 * 72];
    ushort (*kt)[72] = (ushort(*)[72])smem;
    ushort (*vt)[72] = (ushort(*)[72])(smem + 4608);

    const int t = threadIdx.x;
    const int lane = t & 63;
    const int w = t >> 6;
    const int c = lane & 15, g = lane >> 4;
    ushort* ptw = smem + 9216 + w * 1152;          // wave-private [16][72]
    const int bh = blockIdx.y;
    const int n = bh >> 4, h = bh & 15;
    const int l0 = blockIdx.x * 128;
    const int lrow = l0 + w * 16 + c;              // this lane's q row

    // Q B-fragment: lane needs Q[q=c][k=g*8+e]
    bf16x8 aq0 = *(const bf16x8*)(Qa + ((size_t)bh * 2048 + lrow) * 64 + g * 8);
    bf16x8 aq1 = *(const bf16x8*)(Qa + ((size_t)bh * 2048 + lrow) * 64 + 32 + g * 8);

    f32x4 O[4] = {};             // O[dt][r] = O[q=c][d=dt*16+4g+r]
    float m = -1e30f, l = 0.f;   // per-lane online softmax state for q=c

    for (int st = 0; st < 32; ++st) {
        __syncthreads();
        {
            int row = t >> 3, seg = t & 7;
            *(uint4*)&kt[row][seg * 8] =
                *(const uint4*)(Ka + ((size_t)bh * 2048 + st * 64 + row) * 64 + seg * 8);
            *(uint4*)&vt[row][seg * 8] =
                *(const uint4*)(Vt + ((size_t)bh * 64 + row) * 2048 + st * 64 + seg * 8);
        }
        __syncthreads();

        // S^T = mfma(A=K, B=Q): sc[ct][r] = S[kv=ct*16+4g+r][q=c]
        f32x4 sc[4];
#pragma unroll
        for (int ct = 0; ct < 4; ++ct) {
            bf16x8 kb0 = *(const bf16x8*)&kt[ct * 16 + c][g * 8];
            bf16x8 kb1 = *(const bf16x8*)&kt[ct * 16 + c][32 + g * 8];
            f32x4 z = {};
            z = MFMA(kb0, aq0, z);
            sc[ct] = MFMA(kb1, aq1, z);
        }

        // row max: local 16 + cross-group (xor16 merges g-pairs, xor32 halves)
        float pm = fmaxf(fmaxf(sc[0][0], sc[0][1]), fmaxf(sc[0][2], sc[0][3]));
#pragma unroll
        for (int ct = 1; ct < 4; ++ct)
            pm = fmaxf(pm, fmaxf(fmaxf(sc[ct][0], sc[ct][1]), fmaxf(sc[ct][2], sc[ct][3])));
        pm = fmaxf(pm, __shfl_xor(pm, 16));
        pm = fmaxf(pm, __shfl_xor(pm, 32));

        float mn = fmaxf(m, pm);
        float al = exp2f(m - mn);
        m = mn;
        l *= al;
        O[0] *= al; O[1] *= al; O[2] *= al; O[3] *= al;   // lane-local rescale

        // P = exp2(S - m), pack to bf16 pairs, wave-private LDS (b64 writes)
#pragma unroll
        for (int ct = 0; ct < 4; ++ct) {
            float p0 = exp2f(sc[ct][0] - m);
            float p1 = exp2f(sc[ct][1] - m);
            float p2 = exp2f(sc[ct][2] - m);
            float p3 = exp2f(sc[ct][3] - m);
            l += (p0 + p1) + (p2 + p3);
            uint pa, pb;
            asm("v_cvt_pk_bf16_f32 %0, %1, %2" : "=v"(pa) : "v"(p0), "v"(p1));
            asm("v_cvt_pk_bf16_f32 %0, %1, %2" : "=v"(pb) : "v"(p2), "v"(p3));
            uint64_t pk = (uint64_t)pa | ((uint64_t)pb << 32);
            *(s16x4*)&ptw[c * 72 + ct * 16 + g * 4] = __builtin_bit_cast(s16x4, pk);
        }

        // O^T = mfma(A=V^T, B=P): A[d][kv]=vt[d][kv], B[q][kv]=ptw[q][kv]
        bf16x8 ap0 = *(const bf16x8*)&ptw[c * 72 + g * 8];
        bf16x8 ap1 = *(const bf16x8*)&ptw[c * 72 + 32 + g * 8];
#pragma unroll
        for (int dt = 0; dt < 4; ++dt) {
            bf16x8 vb0 = *(const bf16x8*)&vt[dt * 16 + c][g * 8];
            bf16x8 vb1 = *(const bf16x8*)&vt[dt * 16 + c][32 + g * 8];
            O[dt] = MFMA(vb0, ap0, O[dt]);
            O[dt] = MFMA(vb1, ap1, O[dt]);
        }
    }

    // final denom for q=c
    float lsum = l;
    lsum += __shfl_xor(lsum, 16);
    lsum += __shfl_xor(lsum, 32);
    float rl = 1.0f / lsum;

    // transpose O through LDS (pad 65 to spread banks), coalesced ctx write
    __syncthreads();
    float* otw = (float*)smem + w * 1040;          // wave-private [16][65]
#pragma unroll
    for (int dt = 0; dt < 4; ++dt)
#pragma unroll
        for (int r = 0; r < 4; ++r)
            otw[c * 65 + dt * 16 + 4 * g + r] = O[dt][r] * rl;
#pragma unroll
    for (int qq = 0; qq < 16; ++qq) {
        float v = otw[qq * 65 + lane];
        int lr2 = l0 + w * 16 + qq;
        ctx[((size_t)lr2 * 4 + n) * 1024 + h * 64 + lane] = f2bf(v);
    }
    if (g == 0) {
        mbuf[(size_t)bh * 2048 + l0 + w * 16 + c] = m;
        lbuf[(size_t)bh * 2048 + l0 + w * 16 + c] = lsum;
    }
}

// ---------------------------------------------------------------------------
// K3: output projection  out = ctx @ Wo^T + bo  (bf16 Wo pre-converted)
// ---------------------------------------------------------------------------
__global__ __launch_bounds__(256) void k_oproj(
    const ushort* __restrict__ ctx, const ushort* __restrict__ Wob,
    const float* __restrict__ bo, float* __restrict__ out)
{
    __shared__ __align__(16) ushort xt[128][40];
    __shared__ __align__(16) ushort wt[128][40];

    const int t = threadIdx.x;
    const int lane = t & 63;
    const int w = t >> 6;
    const int wr = w >> 1, wc = w & 1;
    const int c = lane & 15, g = lane >> 4;

    const int r0 = blockIdx.x * 128;
    const int e0 = blockIdx.y * 128;

    f32x4 acc[4][4] = {};

    for (int kt = 0; kt < 32; ++kt) {
        const int k0 = kt * 32;
        __syncthreads();
#pragma unroll
        for (int i = 0; i < 2; ++i) {
            int slot = t + i * 256;
            int row = slot >> 2, seg = slot & 3;
            *(uint4*)&xt[row][seg * 8] =
                *(const uint4*)(ctx + (size_t)(r0 + row) * 1024 + k0 + seg * 8);
            *(uint4*)&wt[row][seg * 8] =
                *(const uint4*)(Wob + (size_t)(e0 + row) * 1024 + k0 + seg * 8);
        }
        __syncthreads();

        bf16x8 af[4], bfr[4];
#pragma unroll
        for (int m = 0; m < 4; ++m) af[m]  = *(const bf16x8*)&xt[wr * 64 + m * 16 + c][g * 8];
#pragma unroll
        for (int n = 0; n < 4; ++n) bfr[n] = *(const bf16x8*)&wt[wc * 64 + n * 16 + c][g * 8];
#pragma unroll
        for (int m = 0; m < 4; ++m)
#pragma unroll
            for (int n = 0; n < 4; ++n)
                acc[m][n] = MFMA(af[m], bfr[n], acc[m][n]);
    }

#pragma unroll
    for (int m = 0; m < 4; ++m)
#pragma unroll
        for (int n = 0; n < 4; ++n)
#pragma unroll
            for (int i = 0; i < 4; ++i) {
                int r = r0 + wr * 64 + m * 16 + 4 * g + i;
                int e = e0 + wc * 64 + n * 16 + c;
                out[(size_t)r * 1024 + e] = acc[m][n][i] + bo[e];
            }
}

// ---------------------------------------------------------------------------
// K4: head-averaged attention weights. R5: occupancy-oriented rewrite.
// Grid (16,32,4): block covers l 64 x s 128 for one n. Waves: wr=w&3 picks
// l-subtile (16 rows), wc=w>>2 picks s-half (64); 4 ct subtiles of 16 cols.
// acc[4] f32x4 = 16 VGPR. Normalization folded into exponent:
// ms2[h][row] = m + log2(16*l)  =>  contribution = exp2(score - ms2).
// ---------------------------------------------------------------------------
__global__ __launch_bounds__(512, 8) void k_avg(
    const ushort* __restrict__ Qa, const ushort* __restrict__ Ka,
    const float* __restrict__ mbuf, const float* __restrict__ lbuf,
    float* __restrict__ avg)
{
    __shared__ float ms2[16][64];

    const int t = threadIdx.x;
    const int lane = t & 63;
    const int w = t >> 6;
    const int wr = w & 3, wc = w >> 2;
    const int c = lane & 15, g = lane >> 4;
    const int n = blockIdx.z;
    const int l0 = blockIdx.y * 64;
    const int s0 = blockIdx.x * 128;

    for (int idx = t; idx < 1024; idx += 512) {
        int hh = idx >> 6, row = idx & 63;
        float mv = mbuf[(size_t)(n * 16 + hh) * 2048 + l0 + row];
        float lv = lbuf[(size_t)(n * 16 + hh) * 2048 + l0 + row];
        ms2[hh][row] = mv + __log2f(16.0f * lv);
    }
    __syncthreads();

    f32x4 acc[4] = {};
    const ushort* qp = Qa + ((size_t)(n * 16) * 2048 + l0 + wr * 16 + c) * 64 + g * 8;
    const ushort* kp0 = Ka + ((size_t)(n * 16) * 2048 + s0 + wc * 64 + c) * 64 + g * 8;

    for (int h = 0; h < 16; ++h) {
        const size_t hoff = (size_t)h * 2048 * 64;
        bf16x8 aq0 = *(const bf16x8*)(qp + hoff);
        bf16x8 aq1 = *(const bf16x8*)(qp + hoff + 32);
        f32x4 mr2 = *(const f32x4*)&ms2[h][wr * 16 + 4 * g];
#pragma unroll
        for (int ct = 0; ct < 4; ++ct) {
            const ushort* kp = kp0 + hoff + (size_t)ct * 16 * 64;
            bf16x8 b0 = *(const bf16x8*)kp;
            bf16x8 b1 = *(const bf16x8*)(kp + 32);
            f32x4 zf = {};
            zf = MFMA(aq0, b0, zf);
            zf = MFMA(aq1, b1, zf);
#pragma unroll
            for (int i = 0; i < 4; ++i)
                acc[ct][i] += exp2f(zf[i] - mr2[i]);
        }
    }

#pragma unroll
    for (int ct = 0; ct < 4; ++ct)
#pragma unroll
        for (int i = 0; i < 4; ++i) {
            int row = l0 + wr * 16 + 4 * g + i;
            avg[((size_t)n * 2048 + row) * 2048 + s0 + wc * 64 + ct * 16 + c] = acc[ct][i];
        }
}

// ---------------------------------------------------------------------------
extern "C" void kernel_launch(void* const* d_in, const int* in_sizes, int n_in,
                              void* d_out, int out_size, void* d_ws, size_t ws_size,
                              hipStream_t stream)
{
    const float* query = (const float*)d_in[0];
    const float* key   = (const float*)d_in[1];
    const float* value = (const float*)d_in[2];
    const float* Wq = (const float*)d_in[3];
    const float* bq = (const float*)d_in[4];
    const float* Wk = (const float*)d_in[5];
    const float* bk = (const float*)d_in[6];
    const float* Wv = (const float*)d_in[7];
    const float* bv = (const float*)d_in[8];
    const float* Wo = (const float*)d_in[9];
    const float* bo = (const float*)d_in[10];

    float* out = (float*)d_out;                 // attn_output: 8,388,608 f32
    float* avg = out + 8388608;                 // avg_weights: 16,777,216 f32

    // Workspace (34.6 MB): Qa, Ka bf16; m/l stats.
    ushort* Qa = (ushort*)d_ws;                 // 8,388,608 bf16
    ushort* Ka = Qa + 8388608;                  // 8,388,608 bf16
    float* mbuf = (float*)(Ka + 8388608);       // 131,072 f32
    float* lbuf = mbuf + 131072;                // 131,072 f32

    // Scratch parked in d_out (lifetimes ordered by launch sequence):
    //   out region  (16,777,216 ushorts): Xbq | Xbk    (die before k_oproj)
    //   avg region  (33,554,432 ushorts):
    //     Vt  [0 .. 8,388,608)            (dies at k_avg)
    //     Xbv [8,388,608 .. 16,777,216)   (dies after k_proj)
    //     Wb  [16,777,216 .. 20,971,520)  (Wqb,Wkb,Wvb,Wob; die before k_avg)
    //     ctx [25,165,824 .. 33,554,432)  (dies at k_avg)
    ushort* ob  = (ushort*)out;
    ushort* av16 = (ushort*)avg;
    ushort* Xbq = ob;
    ushort* Xbk = ob + 8388608;
    ushort* Vt  = av16;
    ushort* Xbv = av16 + 8388608;
    ushort* Wqb = av16 + 16777216;
    ushort* Wkb = Wqb + 1048576;
    ushort* Wvb = Wkb + 1048576;
    ushort* Wob = Wvb + 1048576;
    ushort* ctx = av16 + 25165824;

    k_prep<<<dim3(4096, 7), 256, 0, stream>>>(query, key, value, Wq, Wk, Wv, Wo,
                                              Xbq, Xbk, Xbv, Wqb, Wkb, Wvb, Wob);
    k_proj<<<dim3(64, 8, 3), 256, 0, stream>>>(Xbq, Xbk, Xbv, Wqb, Wkb, Wvb,
                                               bq, bk, bv, Qa, Ka, Vt);
    k_attn<<<dim3(16, 64), 512, 0, stream>>>(Qa, Ka, Vt, ctx, mbuf, lbuf);
    k_oproj<<<dim3(64, 8), 256, 0, stream>>>(ctx, Wob, bo, out);
    k_avg<<<dim3(16, 32, 4), 512, 0, stream>>>(Qa, Ka, mbuf, lbuf, avg);
}